// Round 5
// baseline (4852.866 us; speedup 1.0000x reference)
//
#include <hip/hip_runtime.h>
#include <hip/hip_bf16.h>
#include <stdint.h>

// ---------------------------------------------------------------------------
// 2-layer GRU, B=64 S=2048 IN=208 H=100 OUT=98.
//   1) gemm_bias: xg0 = seq @ w_ih_l0^T + b_ih_l0        (fp32 GEMM)
//   2) gru_fused_mfma: BOTH GRU layers, 4 blocks x 16 batches, MFMA matvecs.
//      M = gate rows (7 groups of 16), N = 16 batches, K = 100 -> 128 padded,
//      f16 weights in VGPR A-frags; h in LDS (f16) read as B-frags.
//      Biases folded via ones-column at k=100. Double-buffered hs -> 1 barrier.
//      L1 lags L0 by one step (xg1 = W_ih1 @ y0 on the fly).
//   3) gemm_bias: out = y1 @ w_out^T + b_out             (fp32 GEMM)
// ---------------------------------------------------------------------------

typedef __fp16 half8  __attribute__((ext_vector_type(8)));
typedef __fp16 half2v __attribute__((ext_vector_type(2)));
typedef float  floatx4 __attribute__((ext_vector_type(4)));

#define MFMA16(A, B, C) __builtin_amdgcn_mfma_f32_16x16x32_f16(A, B, C, 0, 0, 0)

__device__ __forceinline__ float fsig(float x)  { return 1.f / (1.f + __expf(-x)); }
__device__ __forceinline__ float ftanh(float x) { return 1.f - 2.f / (1.f + __expf(2.f * x)); }

__device__ __forceinline__ uint32_t pkh2(float a, float b) {
    half2v h = __builtin_amdgcn_cvt_pkrtz(a, b);
    return __builtin_bit_cast(uint32_t, h);
}

// ---------------------------------------------------------------------------
// Fused 2-layer MFMA scan. Grid = 4 blocks (16 batches each), 448 threads
// (7 waves; wave w owns unit group u0 = 16w, units 0..111, 100..111 padded).
// Per iter t: read B-frags of hs0/hs1 (buf t&1) -> 36 MFMA -> gates ->
// write h f16 to buf (t+1)&1 -> one __syncthreads.
// A-frag: lane holds W~[g*100 + u0 + (lane&15)][k = (lane>>4)*8 + j].
// B-frag: lane holds h[batch = lane&15][k = (lane>>4)*8 + j].
// C/D   : col = lane&15 = batch, row = (lane>>4)*4 + reg = unit offset.
// W~[.][100] = bias (ones-column: hs[.][100] = 1 always).
// ---------------------------------------------------------------------------
__global__ __launch_bounds__(448, 2)
void gru_fused_mfma(const float* __restrict__ xg0,   // (B,Sc,300), b_ih0 added
                    const float* __restrict__ whh0, const float* __restrict__ bhh0,
                    const float* __restrict__ wih1, const float* __restrict__ bih1,
                    const float* __restrict__ whh1, const float* __restrict__ bhh1,
                    const float* __restrict__ h_init,  // (2,64,100)
                    float* __restrict__ h_state,       // (2,64,100) in ws
                    float* __restrict__ y1,            // (B,Sc,100)
                    int Sc, int first)
{
    __shared__ __fp16 hs[2][2][16][136];   // [layer][buf][batch][k], 272B row stride

    const int tid  = threadIdx.x, blk = blockIdx.x;
    const int lane = tid & 63,    w   = tid >> 6;      // wave 0..6
    const int quad = lane >> 4,   col = lane & 15;
    const int u0   = w * 16;

    // ---- zero LDS (pad region must be 0: 0*garbage in MFMA could be NaN) ----
    {
        __fp16* p = &hs[0][0][0][0];
        for (int i = tid; i < 2 * 2 * 16 * 136; i += 448) p[i] = (__fp16)0.f;
    }
    __syncthreads();
    // ones column (never overwritten: updates only touch k < 100)
    if (tid < 16) {
        hs[0][0][tid][100] = (__fp16)1.f; hs[0][1][tid][100] = (__fp16)1.f;
        hs[1][0][tid][100] = (__fp16)1.f; hs[1][1][tid][100] = (__fp16)1.f;
    }

    // ---- A-frags: 9 tiles x 4 k-chunks, f16, register-resident ----
    half8 Wl0[3][4], W1i[3][4], W1h[3][4];
    const int  rrel    = col;
    const bool arow_ok = (u0 + rrel) < 100;
    #pragma unroll
    for (int g = 0; g < 3; g++) {
        const int row = g * 100 + u0 + rrel;           // valid only if arow_ok
        #pragma unroll
        for (int c = 0; c < 4; c++) {
            half8 f0, f1, f2;
            #pragma unroll
            for (int j = 0; j < 8; j++) {
                const int k = c * 32 + quad * 8 + j;
                float v0 = 0.f, v1 = 0.f, v2 = 0.f;
                if (arow_ok) {
                    if (k < 100) {
                        v0 = whh0[row * 100 + k];
                        v1 = wih1[row * 100 + k];
                        v2 = whh1[row * 100 + k];
                    } else if (k == 100) {             // bias column
                        v0 = bhh0[row]; v1 = bih1[row]; v2 = bhh1[row];
                    }
                }
                f0[j] = (__fp16)v0; f1[j] = (__fp16)v1; f2[j] = (__fp16)v2;
            }
            Wl0[g][c] = f0; W1i[g][c] = f1; W1h[g][c] = f2;
        }
    }

    // ---- gate-lane setup ----
    const int  urow = u0 + quad * 4;        // lane's first unit (C rows)
    const bool uok  = (urow < 100);         // group 6: only quad 0 valid
    const int  urc  = uok ? urow : 96;      // clamped for harmless loads
    const int  bb   = blk * 16 + col;       // global batch

    floatx4 h0v = {0.f, 0.f, 0.f, 0.f}, h1v = {0.f, 0.f, 0.f, 0.f};
    const float* hsrc = (first ? h_init : h_state);
    if (uok) {
        h0v = *(const floatx4*)(hsrc + (size_t)bb * 100 + urow);
        h1v = *(const floatx4*)(hsrc + 6400 + (size_t)bb * 100 + urow);
        // init h into BOTH bufs (h1[-1] is read from buf1 at t=1)
        const uint2 p0 = make_uint2(pkh2(h0v[0], h0v[1]), pkh2(h0v[2], h0v[3]));
        const uint2 p1 = make_uint2(pkh2(h1v[0], h1v[1]), pkh2(h1v[2], h1v[3]));
        *(uint2*)&hs[0][0][col][urow] = p0;  *(uint2*)&hs[0][1][col][urow] = p0;
        *(uint2*)&hs[1][0][col][urow] = p1;  *(uint2*)&hs[1][1][col][urow] = p1;
    }

    const float* xgb = xg0 + (size_t)bb * Sc * 300;
    floatx4 xc[3], xn_[3];
    #pragma unroll
    for (int g = 0; g < 3; g++)
        xc[g] = *(const floatx4*)(xgb + g * 100 + urc);   // t = 0
    __syncthreads();

    for (int t = 0; t <= Sc; t++) {
        const int cur = t & 1, wr = cur ^ 1;

        // prefetch next xg0 row (consumed next iter)
        {
            const int tt = min(t + 1, Sc - 1);
            #pragma unroll
            for (int g = 0; g < 3; g++)
                xn_[g] = *(const floatx4*)(xgb + (size_t)tt * 300 + g * 100 + urc);
        }

        // B-frags: hs0 (shared by L0hh + L1ih) and hs1
        half8 B0[4], B1[4];
        #pragma unroll
        for (int c = 0; c < 4; c++) {
            B0[c] = *(const half8*)&hs[0][cur][col][c * 32 + quad * 8];
            B1[c] = *(const half8*)&hs[1][cur][col][c * 32 + quad * 8];
        }

        floatx4 a0[3], a1i[3], a1h[3];
        #pragma unroll
        for (int g = 0; g < 3; g++) {
            a0[g]  = floatx4{0.f, 0.f, 0.f, 0.f};
            a1i[g] = floatx4{0.f, 0.f, 0.f, 0.f};
            a1h[g] = floatx4{0.f, 0.f, 0.f, 0.f};
        }
        #pragma unroll
        for (int c = 0; c < 4; c++) {
            #pragma unroll
            for (int g = 0; g < 3; g++) {
                a1i[g] = MFMA16(W1i[g][c], B0[c], a1i[g]);
                a1h[g] = MFMA16(W1h[g][c], B1[c], a1h[g]);
                a0[g]  = MFMA16(Wl0[g][c], B0[c], a0[g]);
            }
        }

        // ---- L1 update: h1[t-1] from h1[t-2] and y0[t-1] ----
        if (t >= 1 && uok) {
            #pragma unroll
            for (int i = 0; i < 4; i++) {
                const float r = fsig(a1i[0][i] + a1h[0][i]);
                const float z = fsig(a1i[1][i] + a1h[1][i]);
                const float n = ftanh(a1i[2][i] + r * a1h[2][i]);
                h1v[i] = (1.f - z) * n + z * h1v[i];
            }
            *(uint2*)&hs[1][wr][col][urow] =
                make_uint2(pkh2(h1v[0], h1v[1]), pkh2(h1v[2], h1v[3]));
            *(floatx4*)(y1 + ((size_t)bb * Sc + (t - 1)) * 100 + urow) = h1v;
        }
        // ---- L0 update: h0[t] from h0[t-1] and xg0[t] ----
        if (t < Sc && uok) {
            #pragma unroll
            for (int i = 0; i < 4; i++) {
                const float r = fsig(xc[0][i] + a0[0][i]);
                const float z = fsig(xc[1][i] + a0[1][i]);
                const float n = ftanh(xc[2][i] + r * a0[2][i]);
                h0v[i] = (1.f - z) * n + z * h0v[i];
            }
            *(uint2*)&hs[0][wr][col][urow] =
                make_uint2(pkh2(h0v[0], h0v[1]), pkh2(h0v[2], h0v[3]));
        }
        xc[0] = xn_[0]; xc[1] = xn_[1]; xc[2] = xn_[2];
        __syncthreads();
    }

    if (uok) {
        *(floatx4*)(h_state + (size_t)bb * 100 + urow)        = h0v;
        *(floatx4*)(h_state + 6400 + (size_t)bb * 100 + urow) = h1v;
    }
}

// ---------------------------------------------------------------------------
// fp32 tiled GEMM with bias: C[row,n] = sum_k A[row,k]*W[n,k] + bias[n]
// ---------------------------------------------------------------------------
#define GB_BM 64
#define GB_BN 64
#define GB_BK 16

__global__ __launch_bounds__(256)
void gemm_bias(const float* __restrict__ A, const float* __restrict__ W,
               const float* __restrict__ bias, float* __restrict__ C,
               int Sc, long a_bs, long a_ss, long c_bs, long c_ss,
               int N, int K)
{
    __shared__ float As[GB_BK][68];
    __shared__ float Bs[GB_BK][68];
    const int tid = threadIdx.x;
    const int m0 = blockIdx.x * GB_BM;
    const int n0 = blockIdx.y * GB_BN;

    const int lm = tid >> 2;
    const int lk = (tid & 3) << 2;
    const int row = m0 + lm;
    const float* arow = A + (long)(row / Sc) * a_bs + (long)(row % Sc) * a_ss;
    const int wrow = n0 + lm;
    const float* wrp = W + (long)wrow * K;
    const bool wv_ok = (wrow < N);

    const int tx = tid & 15;
    const int ty = tid >> 4;

    float acc[4][4] = {};

    for (int k0 = 0; k0 < K; k0 += GB_BK) {
        float4 av, bv;
        if (k0 + GB_BK <= K) {
            av = *(const float4*)(arow + k0 + lk);
            bv = wv_ok ? *(const float4*)(wrp + k0 + lk) : make_float4(0.f,0.f,0.f,0.f);
        } else {
            av = make_float4(0.f,0.f,0.f,0.f);
            bv = make_float4(0.f,0.f,0.f,0.f);
            const int kb = k0 + lk;
            if (kb + 0 < K) { av.x = arow[kb+0]; if (wv_ok) bv.x = wrp[kb+0]; }
            if (kb + 1 < K) { av.y = arow[kb+1]; if (wv_ok) bv.y = wrp[kb+1]; }
            if (kb + 2 < K) { av.z = arow[kb+2]; if (wv_ok) bv.z = wrp[kb+2]; }
            if (kb + 3 < K) { av.w = arow[kb+3]; if (wv_ok) bv.w = wrp[kb+3]; }
        }
        As[lk+0][lm] = av.x; As[lk+1][lm] = av.y; As[lk+2][lm] = av.z; As[lk+3][lm] = av.w;
        Bs[lk+0][lm] = bv.x; Bs[lk+1][lm] = bv.y; Bs[lk+2][lm] = bv.z; Bs[lk+3][lm] = bv.w;
        __syncthreads();
        #pragma unroll
        for (int kk = 0; kk < GB_BK; kk++) {
            float4 a  = *(const float4*)&As[kk][ty << 2];
            float4 bb = *(const float4*)&Bs[kk][tx << 2];
            float ar[4] = {a.x, a.y, a.z, a.w};
            float br[4] = {bb.x, bb.y, bb.z, bb.w};
            #pragma unroll
            for (int i = 0; i < 4; i++)
                #pragma unroll
                for (int j = 0; j < 4; j++)
                    acc[i][j] += ar[i] * br[j];
        }
        __syncthreads();
    }

    #pragma unroll
    for (int i = 0; i < 4; i++) {
        const int r = m0 + (ty << 2) + i;
        float* crow = C + (long)(r / Sc) * c_bs + (long)(r % Sc) * c_ss;
        #pragma unroll
        for (int j = 0; j < 4; j++) {
            const int col = n0 + (tx << 2) + j;
            if (col < N) crow[col] = acc[i][j] + bias[col];
        }
    }
}

// ---------------------------------------------------------------------------

extern "C" void kernel_launch(void* const* d_in, const int* in_sizes, int n_in,
                              void* d_out, int out_size, void* d_ws, size_t ws_size,
                              hipStream_t stream)
{
    const float* seq    = (const float*)d_in[0];
    const float* h0     = (const float*)d_in[1];   // (2, 64, 100)
    const float* w_ih0  = (const float*)d_in[2];   // (300, 208)
    const float* w_hh0  = (const float*)d_in[3];   // (300, 100)
    const float* b_ih0  = (const float*)d_in[4];
    const float* b_hh0  = (const float*)d_in[5];
    const float* w_ih1  = (const float*)d_in[6];   // (300, 100)
    const float* w_hh1  = (const float*)d_in[7];
    const float* b_ih1  = (const float*)d_in[8];
    const float* b_hh1  = (const float*)d_in[9];
    const float* w_out  = (const float*)d_in[10];  // (98, 100)
    const float* b_out  = (const float*)d_in[11];
    float* out = (float*)d_out;

    const int B = 64, S = 2048, IN = 208, H = 100, G = 300, OUT = 98;

    // largest power-of-2 chunk Sc whose buffers fit the workspace
    int Sc = S;
    while (Sc > 16) {
        size_t need = ((size_t)B * Sc * (G + H) + 2 * (size_t)B * H) * sizeof(float);
        if (need <= ws_size) break;
        Sc >>= 1;
    }
    const int NC = S / Sc;

    float* h_state = (float*)d_ws;                    // (2,64,100)
    float* y1c     = h_state + 2 * (size_t)B * H;     // (B,Sc,100)
    float* xgc     = y1c + (size_t)B * Sc * H;        // (B,Sc,300)

    const dim3 blk(256);
    const dim3 gX((B * Sc) / GB_BM, (G + GB_BN - 1) / GB_BN);
    const dim3 gO((B * Sc) / GB_BM, (OUT + GB_BN - 1) / GB_BN);

    for (int c = 0; c < NC; c++) {
        const int s0 = c * Sc;
        const int first = (c == 0);

        // 1) xg0 = seq @ w_ih0^T + b_ih0
        gemm_bias<<<gX, blk, 0, stream>>>(seq + (long)s0 * IN, w_ih0, b_ih0, xgc,
                                          Sc, (long)S * IN, (long)IN,
                                          (long)Sc * G, (long)G, G, IN);
        // 2) fused 2-layer MFMA scan
        gru_fused_mfma<<<dim3(4), dim3(448), 0, stream>>>(xgc,
                                                          w_hh0, b_hh0, w_ih1, b_ih1,
                                                          w_hh1, b_hh1,
                                                          h0, h_state, y1c, Sc, first);
        // 3) out = y1 @ w_out^T + b_out
        gemm_bias<<<gO, blk, 0, stream>>>(y1c, w_out, b_out, out + (long)s0 * OUT,
                                          Sc, (long)Sc * H, (long)H,
                                          (long)S * OUT, (long)OUT, OUT, H);
    }
}